// Round 8
// baseline (178.656 us; speedup 1.0000x reference)
//
#include <hip/hip_runtime.h>
#include <hip/hip_bf16.h>
#include <math.h>

#define D 384
#define EPS 1e-8f

#define RPB 256            // rows per block: 4 waves x 64
#define CPS 512            // cols per split: 4 positions x 128
#define POS_W 128          // fold granularity
#define NPOS 4
#define NKB 12             // k32 steps per position
#define STG 8192           // one B stage: 4 kq x 128 cols x 16 B

typedef __bf16  bf16x8  __attribute__((ext_vector_type(8)));
typedef float   floatx4 __attribute__((ext_vector_type(4)));

// ---------------- kernel 1: rnorm + normalized bf16 cast + ws init ----------------
__global__ __launch_bounds__(256) void prep_kernel(const float* __restrict__ in,
                                                   float* __restrict__ rnorm,
                                                   __hip_bfloat16* __restrict__ xb,
                                                   unsigned long long* __restrict__ best,
                                                   float* __restrict__ out, int N) {
    int row = blockIdx.x * 4 + (threadIdx.x >> 6);   // one wave per row
    if (blockIdx.x == 0 && threadIdx.x == 0) out[0] = 0.f;   // d_out poisoned each call
    if (row >= N) return;
    int lane = threadIdx.x & 63;
    const float* p = in + (size_t)row * D;
    float v[6];
    float s = 0.f;
#pragma unroll
    for (int c = 0; c < 6; ++c) { v[c] = p[lane + 64 * c]; s += v[c] * v[c]; }
#pragma unroll
    for (int off = 32; off >= 1; off >>= 1) s += __shfl_xor(s, off, 64);
    float rn = 1.0f / fmaxf(sqrtf(s), EPS);
    if (lane == 0) { rnorm[row] = rn; best[row] = 0ull; }    // ws poisoned each call
    __hip_bfloat16* q = xb + (size_t)row * D;
#pragma unroll
    for (int c = 0; c < 6; ++c) q[lane + 64 * c] = __float2bfloat16(v[c] * rn);
}

// ---------------- kernel 2: row-ownership MFMA scan, dbuf B + rotating A ----------------
// Block: 4 waves, owns 256 rows, scans 512 cols (4 positions of 128).
// B double-buffered in LDS (2 x 8 KB), layout [kq][col]x16B -> conflict-free
// b128 frag reads AND glds lane-order compliant. glds for step s+1 issue at
// the TOP of step s, so the barrier entering s+1 drains loads that are a full
// k-step (~400+ cyc) old. A fragments rotate through af[2][4] (distance-1,
// parity-indexed, no copies; A k-index is position-invariant). 2 blocks/CU
// so one block computes while the other sits at its barrier.
__global__ __launch_bounds__(256, 2) void maxdot_rows(const __hip_bfloat16* __restrict__ xb,
                                                      unsigned long long* __restrict__ best) {
    __shared__ char Bs[2 * STG];                     // 16 KB

    const int t    = threadIdx.x;
    const int lane = t & 63;
    const int wv   = t >> 6;
    const int quad = lane >> 4, l16 = lane & 15;
    const int rb   = blockIdx.x >> 4;                // 32 row-blocks
    const int cs   = blockIdx.x & 15;                // 16 col-splits
    const int row0b = rb * RPB;
    const int col0s = cs * CPS;
    const int wrow0 = row0b + wv * 64;

    floatx4 acc[4][8];
#pragma unroll
    for (int mi = 0; mi < 4; ++mi)
#pragma unroll
        for (int ni = 0; ni < 8; ++ni) acc[mi][ni] = (floatx4){0.f, 0.f, 0.f, 0.f};

    float rv[16];
    int   ri[16];
#pragma unroll
    for (int i = 0; i < 16; ++i) { rv[i] = -3.0f; ri[i] = 0; }

    // staging granules: gi = wv*64+lane and +256; col = gi&127, kq = gi>>7
    const int gi0 = wv * 64 + lane, gi1 = gi0 + 256;

    auto stage = [&](int buf, int colbase, int kb) {
        const char* g0 = (const char*)xb + (size_t)(colbase + (gi0 & 127)) * 768 + kb * 64 + (gi0 >> 7) * 16;
        const char* g1 = (const char*)xb + (size_t)(colbase + (gi1 & 127)) * 768 + kb * 64 + (gi1 >> 7) * 16;
        __builtin_amdgcn_global_load_lds((const __attribute__((address_space(1))) void*)g0,
                                         (__attribute__((address_space(3))) void*)(Bs + buf * STG + gi0 * 16), 16, 0, 0);
        __builtin_amdgcn_global_load_lds((const __attribute__((address_space(1))) void*)g1,
                                         (__attribute__((address_space(3))) void*)(Bs + buf * STG + gi1 * 16), 16, 0, 0);
    };
    auto loadA = [&](int kidx, bf16x8* dst) {        // kidx = k32 index, position-invariant
#pragma unroll
        for (int mi = 0; mi < 4; ++mi)
            dst[mi] = *(const bf16x8*)((const char*)xb + (size_t)(wrow0 + mi * 16 + l16) * 768 + kidx * 64 + quad * 16);
    };

    bf16x8 af[2][4];
    stage(0, col0s, 0);
    loadA(0, af[0]);

    for (int pos = 0; pos < NPOS; ++pos) {
        const int colbase = col0s + pos * POS_W;
#pragma unroll
        for (int kb = 0; kb < NKB; ++kb) {
            __syncthreads();                         // drains stage(s)+A issued a full step ago
            const int cur = kb & 1;
            const bool lastS = (pos == NPOS - 1) && (kb == NKB - 1);
            if (!lastS) {                            // stage s+1 into other buffer
                const int kbn = (kb + 1) % NKB;
                const int cbn = (kb == NKB - 1) ? colbase + POS_W : colbase;
                stage(cur ^ 1, cbn, kbn);
                loadA((kb + 1) % NKB, af[cur ^ 1]);  // A for s+1 (pos-invariant)
            }
            const char* bb = Bs + cur * STG;
            bf16x8 bfr[8];
#pragma unroll
            for (int ni = 0; ni < 8; ++ni)
                bfr[ni] = *(const bf16x8*)(bb + quad * 2048 + (ni * 16 + l16) * 16);
#pragma unroll
            for (int mi = 0; mi < 4; ++mi)
#pragma unroll
                for (int ni = 0; ni < 8; ++ni)
                    acc[mi][ni] = __builtin_amdgcn_mfma_f32_16x16x32_bf16(af[cur][mi], bfr[ni], acc[mi][ni], 0, 0, 0);
        }

        // ---- fold position into running (val, col); then zero acc ----
        const bool dg = (colbase < row0b + RPB) && (row0b < colbase + POS_W);
#pragma unroll
        for (int mi = 0; mi < 4; ++mi)
#pragma unroll
            for (int reg = 0; reg < 4; ++reg) {
                const int r = wrow0 + mi * 16 + quad * 4 + reg;
                float d[8];
#pragma unroll
                for (int ni = 0; ni < 8; ++ni) d[ni] = acc[mi][ni][reg];
                if (dg) {
#pragma unroll
                    for (int ni = 0; ni < 8; ++ni)
                        if (colbase + ni * 16 + l16 == r) d[ni] = -2.0f;
                }
                float m = d[0]; int ci = 0;
#pragma unroll
                for (int ni = 1; ni < 8; ++ni) {     // ties -> lower ni (lower col)
                    bool gt = d[ni] > m;
                    m  = gt ? d[ni] : m;
                    ci = gt ? ni : ci;
                }
                const int slot = mi * 4 + reg;
                bool upd = m > rv[slot];             // ties -> earlier position
                rv[slot] = upd ? m : rv[slot];
                ri[slot] = upd ? (colbase + ci * 16 + l16) : ri[slot];
#pragma unroll
                for (int ni = 0; ni < 8; ++ni) acc[mi][ni][reg] = 0.f;
            }
    }

    // ---- final cross-lane reduce over the 16 col-lanes, one atomic per row ----
#pragma unroll
    for (int slot = 0; slot < 16; ++slot) {
        float v = rv[slot]; int ci = ri[slot];
#pragma unroll
        for (int m = 1; m < 16; m <<= 1) {
            float ov = __shfl_xor(v, m, 64);
            int   oi = __shfl_xor(ci, m, 64);
            bool take = (ov > v) || (ov == v && oi < ci);
            v  = take ? ov : v;
            ci = take ? oi : ci;
        }
        if (l16 == 0) {
            const int r = wrow0 + (slot >> 2) * 16 + quad * 4 + (slot & 3);
            unsigned u = __float_as_uint(v);
            u = (u & 0x80000000u) ? ~u : (u | 0x80000000u);
            unsigned long long key = ((unsigned long long)u << 32) | (unsigned)(~ci);
            atomicMax(best + r, key);
        }
    }
}

// ---------------- kernel 3: exact fp32 distance + loss ----------------
__global__ __launch_bounds__(256) void loss_kernel(const float* __restrict__ in,
                                                   const float* __restrict__ rnorm,
                                                   const unsigned long long* __restrict__ best,
                                                   float* __restrict__ out, int N) {
    __shared__ float part[4];
    const int wave = threadIdx.x >> 6, lane = threadIdx.x & 63;
    const int gw = blockIdx.x * 4 + wave;            // 8192 waves: one row each
    float local = 0.f;
    for (int row = gw; row < N; row += 8192) {
        unsigned long long key = best[row];
        int j = (int)(~(unsigned)(key & 0xffffffffull));
        float rni = rnorm[row], rnj = rnorm[j];
        const float* pi = in + (size_t)row * D;
        const float* pj = in + (size_t)j * D;
        float s = 0.f;
#pragma unroll
        for (int c = 0; c < 6; ++c) {
            float xi = pi[lane + 64 * c] * rni;
            float xj = pj[lane + 64 * c] * rnj;
            float dvv = xi - xj + EPS;               // ||x - nn_x + eps||
            s += dvv * dvv;
        }
#pragma unroll
        for (int off = 32; off > 0; off >>= 1) s += __shfl_down(s, off, 64);
        if (lane == 0) local += -logf(sqrtf(s) + EPS);
    }
    if (lane == 0) part[wave] = local;
    __syncthreads();
    if (threadIdx.x == 0)
        atomicAdd(out, (part[0] + part[1] + part[2] + part[3]) / (float)N);
}

extern "C" void kernel_launch(void* const* d_in, const int* in_sizes, int n_in,
                              void* d_out, int out_size, void* d_ws, size_t ws_size,
                              hipStream_t stream) {
    const float* in = (const float*)d_in[0];
    float* out = (float*)d_out;
    const int N = in_sizes[0] / D;                   // 8192

    // workspace layout: rnorm (N f32) | best (N u64) | xb (N*D bf16)
    char* ws = (char*)d_ws;
    float* rnorm = (float*)ws;
    unsigned long long* best = (unsigned long long*)(ws + 64 * 1024);
    __hip_bfloat16* xb = (__hip_bfloat16*)(ws + 192 * 1024);

    prep_kernel<<<N / 4, 256, 0, stream>>>(in, rnorm, xb, best, out, N);
    maxdot_rows<<<512, 256, 0, stream>>>(xb, best);  // 32 rb x 16 cs, 2 blocks/CU
    loss_kernel<<<N / 4, 256, 0, stream>>>(in, rnorm, best, out, N);
}

// Round 9
// 160.031 us; speedup vs baseline: 1.1164x; 1.1164x over previous
//
#include <hip/hip_runtime.h>
#include <hip/hip_bf16.h>
#include <math.h>

#define D 384
#define EPS 1e-8f

#define RPB 256            // rows per block: 4 waves x 64
#define CPS 512            // cols per split: 4 positions x 128
#define POS_W 128          // fold granularity
#define NPOS 4
#define NKB 12             // k32 steps per position
#define STG 8192           // one B stage: 4 kq x 128 cols x 16 B

typedef __bf16  bf16x8  __attribute__((ext_vector_type(8)));
typedef float   floatx4 __attribute__((ext_vector_type(4)));

// ---------------- kernel 1: rnorm + normalized bf16 cast + ws init ----------------
__global__ __launch_bounds__(256) void prep_kernel(const float* __restrict__ in,
                                                   float* __restrict__ rnorm,
                                                   __hip_bfloat16* __restrict__ xb,
                                                   unsigned long long* __restrict__ best,
                                                   float* __restrict__ out, int N) {
    int row = blockIdx.x * 4 + (threadIdx.x >> 6);   // one wave per row
    if (blockIdx.x == 0 && threadIdx.x == 0) out[0] = 0.f;   // d_out poisoned each call
    if (row >= N) return;
    int lane = threadIdx.x & 63;
    const float* p = in + (size_t)row * D;
    float v[6];
    float s = 0.f;
#pragma unroll
    for (int c = 0; c < 6; ++c) { v[c] = p[lane + 64 * c]; s += v[c] * v[c]; }
#pragma unroll
    for (int off = 32; off >= 1; off >>= 1) s += __shfl_xor(s, off, 64);
    float rn = 1.0f / fmaxf(sqrtf(s), EPS);
    if (lane == 0) { rnorm[row] = rn; best[row] = 0ull; }    // ws poisoned each call
    __hip_bfloat16* q = xb + (size_t)row * D;
#pragma unroll
    for (int c = 0; c < 6; ++c) q[lane + 64 * c] = __float2bfloat16(v[c] * rn);
}

// ---------------- kernel 2: row-ownership MFMA scan, dbuf B, JIT A ----------------
// Block: 4 waves, owns 256 rows, scans 512 cols (4 positions of 128).
// B double-buffered in LDS (2 x 8 KB), layout [kq][col]x16B (R7-verified
// conflict-free + glds lane-order compliant). glds for step s+1 issue right
// AFTER the barrier entering step s -> the barrier entering s+1 drains loads
// issued a full MFMA-step (~620 cyc) earlier: no fresh-load drain. A frags
// load just-in-time after the barrier (NO cross-barrier A liveness -- the
// R8 af[2][4] rotation spilled: VGPR cap + 44 MB scratch writes). One
// barrier per k-step; 2 blocks/CU interleave across barriers.
__global__ __launch_bounds__(256, 2) void maxdot_rows(const __hip_bfloat16* __restrict__ xb,
                                                      unsigned long long* __restrict__ best) {
    __shared__ char Bs[2 * STG];                     // 16 KB

    const int t    = threadIdx.x;
    const int lane = t & 63;
    const int wv   = t >> 6;
    const int quad = lane >> 4, l16 = lane & 15;
    const int rb   = blockIdx.x >> 4;                // 32 row-blocks
    const int cs   = blockIdx.x & 15;                // 16 col-splits
    const int row0b = rb * RPB;
    const int col0s = cs * CPS;
    const int wrow0 = row0b + wv * 64;

    floatx4 acc[4][8];
#pragma unroll
    for (int mi = 0; mi < 4; ++mi)
#pragma unroll
        for (int ni = 0; ni < 8; ++ni) acc[mi][ni] = (floatx4){0.f, 0.f, 0.f, 0.f};

    float rv[16];
    int   ri[16];
#pragma unroll
    for (int i = 0; i < 16; ++i) { rv[i] = -3.0f; ri[i] = 0; }

    // staging granules: gi = wv*64+lane and +256; col = gi&127, kq = gi>>7
    const int gi0 = wv * 64 + lane, gi1 = gi0 + 256;

    auto stage = [&](int buf, int colbase, int kb) {
        const char* g0 = (const char*)xb + (size_t)(colbase + (gi0 & 127)) * 768 + kb * 64 + (gi0 >> 7) * 16;
        const char* g1 = (const char*)xb + (size_t)(colbase + (gi1 & 127)) * 768 + kb * 64 + (gi1 >> 7) * 16;
        __builtin_amdgcn_global_load_lds((const __attribute__((address_space(1))) void*)g0,
                                         (__attribute__((address_space(3))) void*)(Bs + buf * STG + gi0 * 16), 16, 0, 0);
        __builtin_amdgcn_global_load_lds((const __attribute__((address_space(1))) void*)g1,
                                         (__attribute__((address_space(3))) void*)(Bs + buf * STG + gi1 * 16), 16, 0, 0);
    };

    stage(0, col0s, 0);                              // first-step drain paid once (cold)

    for (int pos = 0; pos < NPOS; ++pos) {
        const int colbase = col0s + pos * POS_W;
#pragma unroll
        for (int kb = 0; kb < NKB; ++kb) {
            __syncthreads();                         // drains stage(cur): issued a full step ago
            const int cur = kb & 1;                  // NKB even -> parity continuous across pos
            const bool lastS = (pos == NPOS - 1) && (kb == NKB - 1);
            if (!lastS) {                            // issue next stage NOW (drained next barrier)
                const int kbn = (kb + 1) % NKB;
                const int cbn = (kb == NKB - 1) ? colbase + POS_W : colbase;
                stage(cur ^ 1, cbn, kbn);
            }
            // A fragments just-in-time (L2-hot; latency overlaps the ds_reads)
            bf16x8 af[4];
#pragma unroll
            for (int mi = 0; mi < 4; ++mi)
                af[mi] = *(const bf16x8*)((const char*)xb + (size_t)(wrow0 + mi * 16 + l16) * 768 + kb * 64 + quad * 16);
            const char* bb = Bs + cur * STG;
            bf16x8 bfr[8];
#pragma unroll
            for (int ni = 0; ni < 8; ++ni)
                bfr[ni] = *(const bf16x8*)(bb + quad * 2048 + (ni * 16 + l16) * 16);
#pragma unroll
            for (int mi = 0; mi < 4; ++mi)
#pragma unroll
                for (int ni = 0; ni < 8; ++ni)
                    acc[mi][ni] = __builtin_amdgcn_mfma_f32_16x16x32_bf16(af[mi], bfr[ni], acc[mi][ni], 0, 0, 0);
        }

        // ---- fold position into running (val, col); then zero acc ----
        const bool dg = (colbase < row0b + RPB) && (row0b < colbase + POS_W);
#pragma unroll
        for (int mi = 0; mi < 4; ++mi)
#pragma unroll
            for (int reg = 0; reg < 4; ++reg) {
                const int r = wrow0 + mi * 16 + quad * 4 + reg;
                float d[8];
#pragma unroll
                for (int ni = 0; ni < 8; ++ni) d[ni] = acc[mi][ni][reg];
                if (dg) {
#pragma unroll
                    for (int ni = 0; ni < 8; ++ni)
                        if (colbase + ni * 16 + l16 == r) d[ni] = -2.0f;
                }
                float m = d[0]; int ci = 0;
#pragma unroll
                for (int ni = 1; ni < 8; ++ni) {     // ties -> lower ni (lower col)
                    bool gt = d[ni] > m;
                    m  = gt ? d[ni] : m;
                    ci = gt ? ni : ci;
                }
                const int slot = mi * 4 + reg;
                bool upd = m > rv[slot];             // ties -> earlier position
                rv[slot] = upd ? m : rv[slot];
                ri[slot] = upd ? (colbase + ci * 16 + l16) : ri[slot];
#pragma unroll
                for (int ni = 0; ni < 8; ++ni) acc[mi][ni][reg] = 0.f;
            }
    }

    // ---- final cross-lane reduce over the 16 col-lanes, one atomic per row ----
#pragma unroll
    for (int slot = 0; slot < 16; ++slot) {
        float v = rv[slot]; int ci = ri[slot];
#pragma unroll
        for (int m = 1; m < 16; m <<= 1) {
            float ov = __shfl_xor(v, m, 64);
            int   oi = __shfl_xor(ci, m, 64);
            bool take = (ov > v) || (ov == v && oi < ci);
            v  = take ? ov : v;
            ci = take ? oi : ci;
        }
        if (l16 == 0) {
            const int r = wrow0 + (slot >> 2) * 16 + quad * 4 + (slot & 3);
            unsigned u = __float_as_uint(v);
            u = (u & 0x80000000u) ? ~u : (u | 0x80000000u);
            unsigned long long key = ((unsigned long long)u << 32) | (unsigned)(~ci);
            atomicMax(best + r, key);
        }
    }
}

// ---------------- kernel 3: exact fp32 distance + loss (256 atomics total) ----------------
__global__ __launch_bounds__(256) void loss_kernel(const float* __restrict__ in,
                                                   const float* __restrict__ rnorm,
                                                   const unsigned long long* __restrict__ best,
                                                   float* __restrict__ out, int N) {
    __shared__ float part[4];
    const int wave = threadIdx.x >> 6, lane = threadIdx.x & 63;
    const int gw = blockIdx.x * 4 + wave;            // 1024 waves, 8 rows each
    float local = 0.f;
    for (int row = gw; row < N; row += 1024) {
        unsigned long long key = best[row];
        int j = (int)(~(unsigned)(key & 0xffffffffull));
        float rni = rnorm[row], rnj = rnorm[j];
        const float* pi = in + (size_t)row * D;
        const float* pj = in + (size_t)j * D;
        float s = 0.f;
#pragma unroll
        for (int c = 0; c < 6; ++c) {
            float xi = pi[lane + 64 * c] * rni;
            float xj = pj[lane + 64 * c] * rnj;
            float dvv = xi - xj + EPS;               // ||x - nn_x + eps||
            s += dvv * dvv;
        }
#pragma unroll
        for (int off = 32; off > 0; off >>= 1) s += __shfl_down(s, off, 64);
        if (lane == 0) local += -logf(sqrtf(s) + EPS);
    }
    if (lane == 0) part[wave] = local;
    __syncthreads();
    if (threadIdx.x == 0)
        atomicAdd(out, (part[0] + part[1] + part[2] + part[3]) / (float)N);
}

extern "C" void kernel_launch(void* const* d_in, const int* in_sizes, int n_in,
                              void* d_out, int out_size, void* d_ws, size_t ws_size,
                              hipStream_t stream) {
    const float* in = (const float*)d_in[0];
    float* out = (float*)d_out;
    const int N = in_sizes[0] / D;                   // 8192

    // workspace layout: rnorm (N f32) | best (N u64) | xb (N*D bf16)
    char* ws = (char*)d_ws;
    float* rnorm = (float*)ws;
    unsigned long long* best = (unsigned long long*)(ws + 64 * 1024);
    __hip_bfloat16* xb = (__hip_bfloat16*)(ws + 192 * 1024);

    prep_kernel<<<N / 4, 256, 0, stream>>>(in, rnorm, xb, best, out, N);
    maxdot_rows<<<512, 256, 0, stream>>>(xb, best);  // 32 rb x 16 cs, 2 blocks/CU
    loss_kernel<<<256, 256, 0, stream>>>(in, rnorm, best, out, N);
}